// Round 1
// baseline (727.446 us; speedup 1.0000x reference)
//
#include <hip/hip_runtime.h>

typedef unsigned short ushort_t;
typedef short bf16x8 __attribute__((ext_vector_type(8)));
typedef float f32x4 __attribute__((ext_vector_type(4)));

#define B_ 64
#define H_ 512
#define E_ 300
#define V_ 50257
#define S_ 128

// output element offsets (f32 elements)
#define HNEW_OFS ((size_t)64 * 50257)
#define A_OFS    ((size_t)64 * 50257 + 64 * 512)

__device__ __forceinline__ unsigned short f2b(float f) {
  unsigned int u = __builtin_bit_cast(unsigned int, f);
  u = u + 0x7FFFu + ((u >> 16) & 1u);
  return (unsigned short)(u >> 16);
}
__device__ __forceinline__ float fast_tanh(float x) {
  x = fminf(15.f, fmaxf(-15.f, x));
  float e = __expf(-2.f * x);
  return (1.f - e) / (1.f + e);
}
__device__ __forceinline__ float fast_sigmoid(float x) {
  return 1.f / (1.f + __expf(-x));
}

// Raw 4-element load (DT: 0=bf16 buffer, 1=f32 buffer), converted to bf16x4
// only at LDS-write time so the load's vmcnt wait lands in the next k-step.
template <int DT> struct Raw4;
template <> struct Raw4<0> {
  ushort4 v;
  __device__ static Raw4 zero() { return {make_ushort4(0, 0, 0, 0)}; }
};
template <> struct Raw4<1> {
  float4 v;
  __device__ static Raw4 zero() { return {make_float4(0.f, 0.f, 0.f, 0.f)}; }
};
template <int DT>
__device__ __forceinline__ Raw4<DT> ld_raw(const void* p, size_t off);
template <>
__device__ __forceinline__ Raw4<0> ld_raw<0>(const void* p, size_t off) {
  return {*(const ushort4*)((const ushort_t*)p + off)};
}
template <>
__device__ __forceinline__ Raw4<1> ld_raw<1>(const void* p, size_t off) {
  return {*(const float4*)((const float*)p + off)};
}
template <int DT>
__device__ __forceinline__ ushort4 to_b4(Raw4<DT> r);
template <>
__device__ __forceinline__ ushort4 to_b4<0>(Raw4<0> r) { return r.v; }
template <>
__device__ __forceinline__ ushort4 to_b4<1>(Raw4<1> r) {
  return make_ushort4(f2b(r.v.x), f2b(r.v.y), f2b(r.v.z), f2b(r.v.w));
}

// ---------------------------------------------------------------------------
// Generic GEMM: C[M,N](f32) = A[M,K] @ W[N,K]^T + bias. 64x64 tile, 4 waves,
// register-prefetch pipelined staging.
// ---------------------------------------------------------------------------
template <int DTA, int DTW>
__global__ __launch_bounds__(256) void gemm_tile(
    const void* __restrict__ A, int lda,
    const void* __restrict__ W, int ldw, int wofs,
    const float* __restrict__ bias,
    float* __restrict__ C, int ldc,
    int M, int N, int K)
{
  __shared__ ushort_t sA[64 * 40];
  __shared__ ushort_t sB[64 * 40];
  const int tid = threadIdx.x;
  const int n0 = blockIdx.x * 64, m0 = blockIdx.y * 64;
  const int wave = tid >> 6, lane = tid & 63, quad = lane >> 4, l16 = lane & 15;

  f32x4 acc[4];
  #pragma unroll
  for (int i = 0; i < 4; ++i) acc[i] = (f32x4){0.f, 0.f, 0.f, 0.f};

  Raw4<DTA> ra[2];
  Raw4<DTW> rb[2];
  auto fetch = [&](int kt) {
    #pragma unroll
    for (int i = 0; i < 2; ++i) {
      int g = tid + i * 256;
      int row = g >> 3, gc = (g & 7) << 2;
      int gk = kt * 32 + gc;
      int ar = m0 + row, wr = n0 + row;
      ra[i] = Raw4<DTA>::zero();
      rb[i] = Raw4<DTW>::zero();
      if (gk < K && ar < M) ra[i] = ld_raw<DTA>(A, (size_t)ar * lda + gk);
      if (gk < K && wr < N) rb[i] = ld_raw<DTW>(W, (size_t)wr * ldw + wofs + gk);
    }
  };
  const int ksteps = (K + 31) >> 5;
  fetch(0);
  for (int kt = 0; kt < ksteps; ++kt) {
    #pragma unroll
    for (int i = 0; i < 2; ++i) {
      int g = tid + i * 256;
      int row = g >> 3, gc = (g & 7) << 2;
      *(ushort4*)(sA + row * 40 + gc) = to_b4<DTA>(ra[i]);
      *(ushort4*)(sB + row * 40 + gc) = to_b4<DTW>(rb[i]);
    }
    __syncthreads();
    if (kt + 1 < ksteps) fetch(kt + 1);
    bf16x8 af = *(const bf16x8*)(sA + (wave * 16 + l16) * 40 + quad * 8);
    #pragma unroll
    for (int nt = 0; nt < 4; ++nt) {
      bf16x8 bfr = *(const bf16x8*)(sB + (nt * 16 + l16) * 40 + quad * 8);
      acc[nt] = __builtin_amdgcn_mfma_f32_16x16x32_bf16(af, bfr, acc[nt], 0, 0, 0);
    }
    __syncthreads();
  }
  #pragma unroll
  for (int nt = 0; nt < 4; ++nt) {
    #pragma unroll
    for (int reg = 0; reg < 4; ++reg) {
      int row = m0 + wave * 16 + quad * 4 + reg;
      int col = n0 + nt * 16 + l16;
      if (row < M && col < N)
        C[(size_t)row * ldc + col] = acc[nt][reg] + bias[col];
    }
  }
}

// ---------------------------------------------------------------------------
// Attention scores, partial per n-block (no atomics, no init needed):
// scores_part[nb][r] = sum_{h in nb-tile} v[h]*tanh(enc[r]@Wa[h]^T + Gh[b][h])
// ---------------------------------------------------------------------------
__global__ __launch_bounds__(256) void attn_scores(
    const float* __restrict__ enc,     // [8192, 1024]
    const float* __restrict__ Wattn,   // [512, 1536]
    const float* __restrict__ Gh,      // [64, 512]
    const float* __restrict__ vw,      // [512]
    float* __restrict__ scores_part)   // [8, 8192]
{
  __shared__ ushort_t sA[64 * 40];
  __shared__ ushort_t sB[64 * 40];
  const int tid = threadIdx.x;
  const int n0 = blockIdx.x * 64, m0 = blockIdx.y * 64;
  const int wave = tid >> 6, lane = tid & 63, quad = lane >> 4, l16 = lane & 15;

  f32x4 acc[4];
  #pragma unroll
  for (int i = 0; i < 4; ++i) acc[i] = (f32x4){0.f, 0.f, 0.f, 0.f};

  float4 ra[2], rb[2];
  auto fetch = [&](int kt) {
    #pragma unroll
    for (int i = 0; i < 2; ++i) {
      int g = tid + i * 256;
      int row = g >> 3, gc = (g & 7) << 2;
      int gk = kt * 32 + gc;
      ra[i] = *(const float4*)(enc + (size_t)(m0 + row) * 1024 + gk);
      rb[i] = *(const float4*)(Wattn + (size_t)(n0 + row) * 1536 + 512 + gk);
    }
  };
  fetch(0);
  for (int kt = 0; kt < 32; ++kt) {      // K=1024
    #pragma unroll
    for (int i = 0; i < 2; ++i) {
      int g = tid + i * 256;
      int row = g >> 3, gc = (g & 7) << 2;
      *(ushort4*)(sA + row * 40 + gc) =
          make_ushort4(f2b(ra[i].x), f2b(ra[i].y), f2b(ra[i].z), f2b(ra[i].w));
      *(ushort4*)(sB + row * 40 + gc) =
          make_ushort4(f2b(rb[i].x), f2b(rb[i].y), f2b(rb[i].z), f2b(rb[i].w));
    }
    __syncthreads();
    if (kt + 1 < 32) fetch(kt + 1);
    bf16x8 af = *(const bf16x8*)(sA + (wave * 16 + l16) * 40 + quad * 8);
    #pragma unroll
    for (int nt = 0; nt < 4; ++nt) {
      bf16x8 bfr = *(const bf16x8*)(sB + (nt * 16 + l16) * 40 + quad * 8);
      acc[nt] = __builtin_amdgcn_mfma_f32_16x16x32_bf16(af, bfr, acc[nt], 0, 0, 0);
    }
    __syncthreads();
  }
  float psum[4] = {0.f, 0.f, 0.f, 0.f};
  #pragma unroll
  for (int nt = 0; nt < 4; ++nt) {
    int h = n0 + nt * 16 + l16;
    float vh = vw[h];
    #pragma unroll
    for (int reg = 0; reg < 4; ++reg) {
      int r = m0 + wave * 16 + quad * 4 + reg;
      int b = r & 63;
      float e = acc[nt][reg] + Gh[b * 512 + h];
      psum[reg] += vh * fast_tanh(e);
    }
  }
  #pragma unroll
  for (int reg = 0; reg < 4; ++reg) {
    float p = psum[reg];
    p += __shfl_xor(p, 1);
    p += __shfl_xor(p, 2);
    p += __shfl_xor(p, 4);
    p += __shfl_xor(p, 8);
    if (l16 == 0) {
      int r = m0 + wave * 16 + quad * 4 + reg;
      scores_part[blockIdx.x * 8192 + r] = p;
    }
  }
}

// ---------------------------------------------------------------------------
// Per-batch: sum partials + mask + softmax -> a ; context ; build x and xo.
// ---------------------------------------------------------------------------
__global__ __launch_bounds__(256) void softmax_ctx(
    const float* __restrict__ scores_part, // [8, 8192], index nb*8192 + s*64+b
    const int* __restrict__ mask,       // [64, 128]
    const float* __restrict__ enc,      // [128, 64, 1024]
    const float* __restrict__ emb,      // [50257, 300]
    const int* __restrict__ ids,        // [64]
    float* __restrict__ out,            // a at A_OFS
    ushort_t* __restrict__ x,           // [64, 1344]: [emb 0:300 | w 300:1324 | pad]
    ushort_t* __restrict__ xo)          // [64, 1856]: [h 0:512 | w 512:1536 | emb 1536:1836 | pad]
{
  __shared__ float sc[128];
  __shared__ float red[128];
  const int b = blockIdx.x;
  const int tid = threadIdx.x;

  if (tid < 128) {
    float s = 0.f;
    #pragma unroll
    for (int nb = 0; nb < 8; ++nb) s += scores_part[nb * 8192 + tid * 64 + b];
    if (mask[b * 128 + tid] == 0) s = -1e10f;
    sc[tid] = s;
    red[tid] = s;
  }
  __syncthreads();
  for (int off = 64; off > 0; off >>= 1) {
    if (tid < off) red[tid] = fmaxf(red[tid], red[tid + off]);
    __syncthreads();
  }
  float m = red[0];
  __syncthreads();
  if (tid < 128) {
    float e = __expf(sc[tid] - m);
    sc[tid] = e;
    red[tid] = e;
  }
  __syncthreads();
  for (int off = 64; off > 0; off >>= 1) {
    if (tid < off) red[tid] += red[tid + off];
    __syncthreads();
  }
  float inv = 1.f / red[0];
  if (tid < 128) {
    float av = sc[tid] * inv;
    sc[tid] = av;
    out[A_OFS + b * 128 + tid] = av;
  }
  __syncthreads();

  // weighted context over 1024 dims (tid*4)
  {
    int e0 = tid * 4;
    float a0 = 0.f, a1 = 0.f, a2 = 0.f, a3 = 0.f;
    for (int s = 0; s < 128; ++s) {
      float as = sc[s];
      float4 ev = *(const float4*)(enc + (size_t)(s * 64 + b) * 1024 + e0);
      a0 += as * ev.x;
      a1 += as * ev.y;
      a2 += as * ev.z;
      a3 += as * ev.w;
    }
    ushort4 wb = make_ushort4(f2b(a0), f2b(a1), f2b(a2), f2b(a3));
    *(ushort4*)(x + b * 1344 + 300 + e0) = wb;
    *(ushort4*)(xo + b * 1856 + 512 + e0) = wb;
  }

  // embedding gather
  int rid = ids[b];
  for (int e = tid; e < 300; e += 256) {
    ushort_t h = f2b(emb[(size_t)rid * 300 + e]);
    x[b * 1344 + e] = h;
    xo[b * 1856 + 1536 + e] = h;
  }
  // zero pads
  if (tid < 20) {
    x[b * 1344 + 1324 + tid] = 0;
    xo[b * 1856 + 1836 + tid] = 0;
  }
}

// ---------------------------------------------------------------------------
// GRU pointwise: r,z,n -> h_new (to out + xo[:,0:512])
// ---------------------------------------------------------------------------
__global__ __launch_bounds__(256) void gru_pointwise(
    const float* __restrict__ gx,       // [64, 1536]
    const float* __restrict__ gh,       // [64, 1536]
    const float* __restrict__ hidden,   // [64, 512]
    float* __restrict__ out,            // h_new at HNEW_OFS
    ushort_t* __restrict__ xo)          // [64, 1856]
{
  int i = blockIdx.x * 256 + threadIdx.x;   // 0..32767
  int b = i >> 9, h = i & 511;
  float r = fast_sigmoid(gx[b * 1536 + h] + gh[b * 1536 + h]);
  float z = fast_sigmoid(gx[b * 1536 + 512 + h] + gh[b * 1536 + 512 + h]);
  float n = fast_tanh(gx[b * 1536 + 1024 + h] + r * gh[b * 1536 + 1024 + h]);
  float hp = hidden[b * 512 + h];
  float hn = (1.f - z) * n + z * hp;
  out[HNEW_OFS + b * 512 + h] = hn;
  xo[b * 1856 + h] = f2b(hn);
}

// ---------------------------------------------------------------------------
// Output projection v2: pred[64,50257] = xo[64,1836] @ W_out[50257,1836]^T + b_out
// Memory-bound (369 MB of f32 W_out, zero reuse) -> stream B straight
// global->reg->bf16->MFMA (2-step register double-buffer, no LDS bounce).
// Each wave owns 16 output columns for all 64 rows; lane l16 owns one W_out
// row, quad owns the k-slice, so the B MFMA fragment IS the global load.
// Only A (Xo, 4 KB/k-step, reused by all waves) goes through LDS,
// double-buffered with ONE barrier per k-step (vs 2 before).
// K tail: clamp per-float4 k to 1832; clamped lanes hit Xo's zero pads.
// ---------------------------------------------------------------------------
__global__ __launch_bounds__(256) void out_proj2(
    const ushort_t* __restrict__ Xo,     // [64, 1856] bf16 (cols 1836.. zero)
    const float* __restrict__ Wout,      // [50257, 1836] f32
    const float* __restrict__ bout,      // [50257]
    float* __restrict__ pred)            // [64, 50257]
{
  __shared__ ushort_t sA[2][64 * 40];
  const int tid = threadIdx.x;
  const int n0 = blockIdx.x * 64;
  const int wave = tid >> 6, lane = tid & 63, quad = lane >> 4, l16 = lane & 15;

  // this lane's W_out row (= output column)
  const int col = n0 + wave * 16 + l16;
  const int colc = (col < V_) ? col : 0;
  const float* pB = Wout + (size_t)colc * 1836;

  // A staging: thread t covers Xo[t>>2][(t&3)*8 + kt*32 .. +7] (16 B)
  const int arow = tid >> 2;
  const int acol = (tid & 3) * 8;
  const ushort_t* pA = Xo + (size_t)arow * 1856 + acol;
  ushort_t* sAw0 = &sA[0][arow * 40 + acol];
  ushort_t* sAw1 = &sA[1][arow * 40 + acol];

  f32x4 acc[4];
  #pragma unroll
  for (int i = 0; i < 4; ++i) acc[i] = (f32x4){0.f, 0.f, 0.f, 0.f};

  float4 b0a, b0b, b1a, b1b;
  auto ldB = [&](int kt, float4& va, float4& vb) {
    int k0 = kt * 32 + quad * 8;
    int ka = (k0 < 1832) ? k0 : 1832;
    int kb = (k0 + 4 < 1832) ? (k0 + 4) : 1832;
    va = *(const float4*)(pB + ka);
    vb = *(const float4*)(pB + kb);
  };
  auto packB = [](float4 a, float4 b) {
    bf16x8 r;
    r[0] = (short)f2b(a.x); r[1] = (short)f2b(a.y);
    r[2] = (short)f2b(a.z); r[3] = (short)f2b(a.w);
    r[4] = (short)f2b(b.x); r[5] = (short)f2b(b.y);
    r[6] = (short)f2b(b.z); r[7] = (short)f2b(b.w);
    return r;
  };
  auto mfma4 = [&](const ushort_t* base, bf16x8 bf) {
    #pragma unroll
    for (int mt = 0; mt < 4; ++mt) {
      bf16x8 af = *(const bf16x8*)(base + (mt * 16 + l16) * 40 + quad * 8);
      acc[mt] = __builtin_amdgcn_mfma_f32_16x16x32_bf16(af, bf, acc[mt], 0, 0, 0);
    }
  };

  // prologue: sA[0] <- A(0); regs: aReg=A(1), b0=B(0), b1=B(1)
  ldB(0, b0a, b0b);
  bf16x8 aReg = *(const bf16x8*)(pA);
  *(bf16x8*)sAw0 = aReg;
  aReg = *(const bf16x8*)(pA + 32);
  ldB(1, b1a, b1b);
  __syncthreads();

  // 58 k-steps (K=1836 padded to 1856), 2 per iteration (named reg dbuf)
  #pragma unroll 1
  for (int kt = 0; kt < 58; kt += 2) {
    // even step kt: consume b0 + sA[kt&1==0]; stage A(kt+1)->sA[1]
    {
      if (kt + 1 < 58) *(bf16x8*)sAw1 = aReg;
      bf16x8 bf = packB(b0a, b0b);
      if (kt + 2 < 58) {
        ldB(kt + 2, b0a, b0b);
        aReg = *(const bf16x8*)(pA + (size_t)(kt + 2) * 32);
      }
      mfma4(&sA[0][0], bf);
      __syncthreads();
    }
    // odd step kt+1: consume b1 + sA[1]; stage A(kt+2)->sA[0]
    {
      if (kt + 3 < 58) *(bf16x8*)sAw0 = aReg;
      bf16x8 bf = packB(b1a, b1b);
      if (kt + 3 < 58) {
        ldB(kt + 3, b1a, b1b);
        aReg = *(const bf16x8*)(pA + (size_t)(kt + 3) * 32);
      }
      mfma4(&sA[1][0], bf);
      __syncthreads();
    }
  }

  if (col < V_) {
    float bc = bout[col];
    #pragma unroll
    for (int mt = 0; mt < 4; ++mt) {
      #pragma unroll
      for (int reg = 0; reg < 4; ++reg) {
        int prow = mt * 16 + quad * 4 + reg;
        pred[(size_t)prow * V_ + col] = acc[mt][reg] + bc;
      }
    }
  }
}

// ---------------------------------------------------------------------------
extern "C" void kernel_launch(void* const* d_in, const int* in_sizes, int n_in,
                              void* d_out, int out_size, void* d_ws, size_t ws_size,
                              hipStream_t stream) {
  const int*   ids    = (const int*)d_in[0];
  const float* hidden = (const float*)d_in[1];
  const float* enc    = (const float*)d_in[2];
  const int*   mask   = (const int*)d_in[3];
  const float* emb    = (const float*)d_in[4];
  const float* Wattn  = (const float*)d_in[5];
  const float* battn  = (const float*)d_in[6];
  const float* vw     = (const float*)d_in[7];
  const float* Wih    = (const float*)d_in[8];
  const float* Whh    = (const float*)d_in[9];
  const float* bih    = (const float*)d_in[10];
  const float* bhh    = (const float*)d_in[11];
  const float* Wout   = (const float*)d_in[12];
  const float* bout   = (const float*)d_in[13];
  float* out = (float*)d_out;

  char* ws = (char*)d_ws;
  float*    scores_part = (float*)(ws + 0);          // 8*8192 f32 = 256 KB
  float*    Gh          = (float*)(ws + 262144);     // 64*512 f32 = 128 KB
  float*    gx          = (float*)(ws + 393216);     // 64*1536 f32 = 384 KB
  float*    gh          = (float*)(ws + 786432);     // 64*1536 f32 = 384 KB
  ushort_t* x           = (ushort_t*)(ws + 1179648); // 64*1344 bf16 = 168 KB
  ushort_t* xo          = (ushort_t*)(ws + 1351680); // 64*1856 bf16 = 232 KB

  // Gh = hidden @ Wattn[:, 0:512]^T + b_attn
  gemm_tile<1, 1><<<dim3(8, 1), 256, 0, stream>>>(
      hidden, 512, Wattn, 1536, 0, battn, Gh, 512, 64, 512, 512);

  // partial attention scores (fused energy GEMM + tanh + v-dot)
  attn_scores<<<dim3(8, 128), 256, 0, stream>>>(enc, Wattn, Gh, vw, scores_part);

  // softmax + context + build x, xo (+ a output)
  softmax_ctx<<<64, 256, 0, stream>>>(scores_part, mask, enc, emb, ids, out, x, xo);

  // gx = x @ W_ih^T + b_ih ; gh = hidden @ W_hh^T + b_hh
  gemm_tile<0, 1><<<dim3(24, 1), 256, 0, stream>>>(
      x, 1344, Wih, 1324, 0, bih, gx, 1536, 64, 1536, 1324);
  gemm_tile<1, 1><<<dim3(24, 1), 256, 0, stream>>>(
      hidden, 512, Whh, 512, 0, bhh, gh, 1536, 64, 1536, 512);

  // GRU pointwise -> h_new
  gru_pointwise<<<128, 256, 0, stream>>>(gx, gh, hidden, out, xo);

  // prediction = xo @ W_out^T + b_out (B streamed global->reg, no LDS)
  out_proj2<<<786, 256, 0, stream>>>(xo, Wout, bout, out);
}

// Round 2
// 714.796 us; speedup vs baseline: 1.0177x; 1.0177x over previous
//
#include <hip/hip_runtime.h>
#include <hip/hip_bf16.h>

typedef unsigned short ushort_t;
typedef short bf16x8 __attribute__((ext_vector_type(8)));
typedef float f32x4 __attribute__((ext_vector_type(4)));

#define B_ 64
#define H_ 512
#define E_ 300
#define V_ 50257
#define S_ 128

// output element offsets (f32 elements)
#define HNEW_OFS ((size_t)64 * 50257)
#define A_OFS    ((size_t)64 * 50257 + 64 * 512)

// f32 -> bf16 RTNE via compiler cast: on gfx950 adjacent pairs fuse into
// v_cvt_pk_bf16_f32 (1 op / 2 elems) instead of ~4 integer VALU ops/elem.
__device__ __forceinline__ ushort_t f2b(float f) {
  return __builtin_bit_cast(ushort_t, __float2bfloat16(f));
}
__device__ __forceinline__ float fast_tanh(float x) {
  x = fminf(15.f, fmaxf(-15.f, x));
  float e = __expf(-2.f * x);
  return (1.f - e) / (1.f + e);
}
__device__ __forceinline__ float fast_sigmoid(float x) {
  return 1.f / (1.f + __expf(-x));
}

// Raw 4-element load (DT: 0=bf16 buffer, 1=f32 buffer), converted to bf16x4
// only at LDS-write time so the load's vmcnt wait lands in the next k-step.
template <int DT> struct Raw4;
template <> struct Raw4<0> {
  ushort4 v;
  __device__ static Raw4 zero() { return {make_ushort4(0, 0, 0, 0)}; }
};
template <> struct Raw4<1> {
  float4 v;
  __device__ static Raw4 zero() { return {make_float4(0.f, 0.f, 0.f, 0.f)}; }
};
template <int DT>
__device__ __forceinline__ Raw4<DT> ld_raw(const void* p, size_t off);
template <>
__device__ __forceinline__ Raw4<0> ld_raw<0>(const void* p, size_t off) {
  return {*(const ushort4*)((const ushort_t*)p + off)};
}
template <>
__device__ __forceinline__ Raw4<1> ld_raw<1>(const void* p, size_t off) {
  return {*(const float4*)((const float*)p + off)};
}
template <int DT>
__device__ __forceinline__ ushort4 to_b4(Raw4<DT> r);
template <>
__device__ __forceinline__ ushort4 to_b4<0>(Raw4<0> r) { return r.v; }
template <>
__device__ __forceinline__ ushort4 to_b4<1>(Raw4<1> r) {
  return make_ushort4(f2b(r.v.x), f2b(r.v.y), f2b(r.v.z), f2b(r.v.w));
}

// ---------------------------------------------------------------------------
// Generic GEMM: C[M,N](f32) = A[M,K] @ W[N,K]^T + bias. 64x64 tile, 4 waves.
// LDS double-buffered: ONE barrier per k-step (was 2), 2-step reg prefetch.
// ---------------------------------------------------------------------------
template <int DTA, int DTW>
__global__ __launch_bounds__(256) void gemm_tile(
    const void* __restrict__ A, int lda,
    const void* __restrict__ W, int ldw, int wofs,
    const float* __restrict__ bias,
    float* __restrict__ C, int ldc,
    int M, int N, int K)
{
  __shared__ ushort_t sA[2][64 * 40];
  __shared__ ushort_t sB[2][64 * 40];
  const int tid = threadIdx.x;
  const int n0 = blockIdx.x * 64, m0 = blockIdx.y * 64;
  const int wave = tid >> 6, lane = tid & 63, quad = lane >> 4, l16 = lane & 15;

  f32x4 acc[4];
  #pragma unroll
  for (int i = 0; i < 4; ++i) acc[i] = (f32x4){0.f, 0.f, 0.f, 0.f};

  Raw4<DTA> ra[2];
  Raw4<DTW> rb[2];
  auto fetch = [&](int kt) {
    #pragma unroll
    for (int i = 0; i < 2; ++i) {
      int g = tid + i * 256;
      int row = g >> 3, gc = (g & 7) << 2;
      int gk = kt * 32 + gc;
      int ar = m0 + row, wr = n0 + row;
      ra[i] = Raw4<DTA>::zero();
      rb[i] = Raw4<DTW>::zero();
      if (gk < K && ar < M) ra[i] = ld_raw<DTA>(A, (size_t)ar * lda + gk);
      if (gk < K && wr < N) rb[i] = ld_raw<DTW>(W, (size_t)wr * ldw + wofs + gk);
    }
  };
  auto stage = [&](int buf) {
    #pragma unroll
    for (int i = 0; i < 2; ++i) {
      int g = tid + i * 256;
      int row = g >> 3, gc = (g & 7) << 2;
      *(ushort4*)(sA[buf] + row * 40 + gc) = to_b4<DTA>(ra[i]);
      *(ushort4*)(sB[buf] + row * 40 + gc) = to_b4<DTW>(rb[i]);
    }
  };
  const int ksteps = (K + 31) >> 5;
  fetch(0);
  stage(0);
  if (ksteps > 1) fetch(1);
  __syncthreads();
  for (int kt = 0; kt < ksteps; ++kt) {
    if (kt + 1 < ksteps) stage((kt + 1) & 1);
    if (kt + 2 < ksteps) fetch(kt + 2);
    bf16x8 af = *(const bf16x8*)(sA[kt & 1] + (wave * 16 + l16) * 40 + quad * 8);
    #pragma unroll
    for (int nt = 0; nt < 4; ++nt) {
      bf16x8 bfr = *(const bf16x8*)(sB[kt & 1] + (nt * 16 + l16) * 40 + quad * 8);
      acc[nt] = __builtin_amdgcn_mfma_f32_16x16x32_bf16(af, bfr, acc[nt], 0, 0, 0);
    }
    __syncthreads();
  }
  #pragma unroll
  for (int nt = 0; nt < 4; ++nt) {
    #pragma unroll
    for (int reg = 0; reg < 4; ++reg) {
      int row = m0 + wave * 16 + quad * 4 + reg;
      int col = n0 + nt * 16 + l16;
      if (row < M && col < N)
        C[(size_t)row * ldc + col] = acc[nt][reg] + bias[col];
    }
  }
}

// ---------------------------------------------------------------------------
// Attention scores, partial per n-block (no atomics, no init needed):
// scores_part[nb][r] = sum_{h in nb-tile} v[h]*tanh(enc[r]@Wa[h]^T + Gh[b][h])
// LDS double-buffered, 1 barrier/k-step.
// ---------------------------------------------------------------------------
__global__ __launch_bounds__(256) void attn_scores(
    const float* __restrict__ enc,     // [8192, 1024]
    const float* __restrict__ Wattn,   // [512, 1536]
    const float* __restrict__ Gh,      // [64, 512]
    const float* __restrict__ vw,      // [512]
    float* __restrict__ scores_part)   // [8, 8192]
{
  __shared__ ushort_t sA[2][64 * 40];
  __shared__ ushort_t sB[2][64 * 40];
  const int tid = threadIdx.x;
  const int n0 = blockIdx.x * 64, m0 = blockIdx.y * 64;
  const int wave = tid >> 6, lane = tid & 63, quad = lane >> 4, l16 = lane & 15;

  f32x4 acc[4];
  #pragma unroll
  for (int i = 0; i < 4; ++i) acc[i] = (f32x4){0.f, 0.f, 0.f, 0.f};

  float4 ra[2], rb[2];
  auto fetch = [&](int kt) {
    #pragma unroll
    for (int i = 0; i < 2; ++i) {
      int g = tid + i * 256;
      int row = g >> 3, gc = (g & 7) << 2;
      int gk = kt * 32 + gc;
      ra[i] = *(const float4*)(enc + (size_t)(m0 + row) * 1024 + gk);
      rb[i] = *(const float4*)(Wattn + (size_t)(n0 + row) * 1536 + 512 + gk);
    }
  };
  auto stage = [&](int buf) {
    #pragma unroll
    for (int i = 0; i < 2; ++i) {
      int g = tid + i * 256;
      int row = g >> 3, gc = (g & 7) << 2;
      *(ushort4*)(sA[buf] + row * 40 + gc) =
          make_ushort4(f2b(ra[i].x), f2b(ra[i].y), f2b(ra[i].z), f2b(ra[i].w));
      *(ushort4*)(sB[buf] + row * 40 + gc) =
          make_ushort4(f2b(rb[i].x), f2b(rb[i].y), f2b(rb[i].z), f2b(rb[i].w));
    }
  };
  fetch(0);
  stage(0);
  fetch(1);
  __syncthreads();
  for (int kt = 0; kt < 32; ++kt) {      // K=1024
    if (kt + 1 < 32) stage((kt + 1) & 1);
    if (kt + 2 < 32) fetch(kt + 2);
    bf16x8 af = *(const bf16x8*)(sA[kt & 1] + (wave * 16 + l16) * 40 + quad * 8);
    #pragma unroll
    for (int nt = 0; nt < 4; ++nt) {
      bf16x8 bfr = *(const bf16x8*)(sB[kt & 1] + (nt * 16 + l16) * 40 + quad * 8);
      acc[nt] = __builtin_amdgcn_mfma_f32_16x16x32_bf16(af, bfr, acc[nt], 0, 0, 0);
    }
    __syncthreads();
  }
  float psum[4] = {0.f, 0.f, 0.f, 0.f};
  #pragma unroll
  for (int nt = 0; nt < 4; ++nt) {
    int h = n0 + nt * 16 + l16;
    float vh = vw[h];
    #pragma unroll
    for (int reg = 0; reg < 4; ++reg) {
      int r = m0 + wave * 16 + quad * 4 + reg;
      int b = r & 63;
      float e = acc[nt][reg] + Gh[b * 512 + h];
      psum[reg] += vh * fast_tanh(e);
    }
  }
  #pragma unroll
  for (int reg = 0; reg < 4; ++reg) {
    float p = psum[reg];
    p += __shfl_xor(p, 1);
    p += __shfl_xor(p, 2);
    p += __shfl_xor(p, 4);
    p += __shfl_xor(p, 8);
    if (l16 == 0) {
      int r = m0 + wave * 16 + quad * 4 + reg;
      scores_part[blockIdx.x * 8192 + r] = p;
    }
  }
}

// ---------------------------------------------------------------------------
// Per-batch: sum partials + mask + softmax -> a ; context ; build x and xo.
// ---------------------------------------------------------------------------
__global__ __launch_bounds__(256) void softmax_ctx(
    const float* __restrict__ scores_part, // [8, 8192], index nb*8192 + s*64+b
    const int* __restrict__ mask,       // [64, 128]
    const float* __restrict__ enc,      // [128, 64, 1024]
    const float* __restrict__ emb,      // [50257, 300]
    const int* __restrict__ ids,        // [64]
    float* __restrict__ out,            // a at A_OFS
    ushort_t* __restrict__ x,           // [64, 1344]: [emb 0:300 | w 300:1324 | pad]
    ushort_t* __restrict__ xo)          // [64, 1856]: [h 0:512 | w 512:1536 | emb 1536:1836 | pad]
{
  __shared__ float sc[128];
  __shared__ float red[128];
  const int b = blockIdx.x;
  const int tid = threadIdx.x;

  if (tid < 128) {
    float s = 0.f;
    #pragma unroll
    for (int nb = 0; nb < 8; ++nb) s += scores_part[nb * 8192 + tid * 64 + b];
    if (mask[b * 128 + tid] == 0) s = -1e10f;
    sc[tid] = s;
    red[tid] = s;
  }
  __syncthreads();
  for (int off = 64; off > 0; off >>= 1) {
    if (tid < off) red[tid] = fmaxf(red[tid], red[tid + off]);
    __syncthreads();
  }
  float m = red[0];
  __syncthreads();
  if (tid < 128) {
    float e = __expf(sc[tid] - m);
    sc[tid] = e;
    red[tid] = e;
  }
  __syncthreads();
  for (int off = 64; off > 0; off >>= 1) {
    if (tid < off) red[tid] += red[tid + off];
    __syncthreads();
  }
  float inv = 1.f / red[0];
  if (tid < 128) {
    float av = sc[tid] * inv;
    sc[tid] = av;
    out[A_OFS + b * 128 + tid] = av;
  }
  __syncthreads();

  // weighted context over 1024 dims (tid*4)
  {
    int e0 = tid * 4;
    float a0 = 0.f, a1 = 0.f, a2 = 0.f, a3 = 0.f;
    for (int s = 0; s < 128; ++s) {
      float as = sc[s];
      float4 ev = *(const float4*)(enc + (size_t)(s * 64 + b) * 1024 + e0);
      a0 += as * ev.x;
      a1 += as * ev.y;
      a2 += as * ev.z;
      a3 += as * ev.w;
    }
    ushort4 wb = make_ushort4(f2b(a0), f2b(a1), f2b(a2), f2b(a3));
    *(ushort4*)(x + b * 1344 + 300 + e0) = wb;
    *(ushort4*)(xo + b * 1856 + 512 + e0) = wb;
  }

  // embedding gather
  int rid = ids[b];
  for (int e = tid; e < 300; e += 256) {
    ushort_t h = f2b(emb[(size_t)rid * 300 + e]);
    x[b * 1344 + e] = h;
    xo[b * 1856 + 1536 + e] = h;
  }
  // zero pads
  if (tid < 20) {
    x[b * 1344 + 1324 + tid] = 0;
    xo[b * 1856 + 1836 + tid] = 0;
  }
}

// ---------------------------------------------------------------------------
// Fused gx/gh GEMM (one launch, role by blockIdx.y):
//   y=0: gx[64,1536] = x(bf16)[64,1344(pad0)] @ Wih[1536,1324]^T + bih
//   y=1: gh[64,1536] = hidden(f32)[64,512]    @ Whh[1536,512]^T  + bhh
// LDS double-buffered, 1 barrier/k-step.
// ---------------------------------------------------------------------------
__global__ __launch_bounds__(256) void gemm_gxgh(
    const ushort_t* __restrict__ xb,    // [64, 1344] bf16, cols 1324.. zero
    const float* __restrict__ hidden,   // [64, 512]
    const float* __restrict__ Wih,      // [1536, 1324]
    const float* __restrict__ Whh,      // [1536, 512]
    const float* __restrict__ bih,
    const float* __restrict__ bhh,
    float* __restrict__ gxo,            // [64, 1536]
    float* __restrict__ gho)            // [64, 1536]
{
  __shared__ ushort_t sA[2][64 * 40];
  __shared__ ushort_t sB[2][64 * 40];
  const int tid = threadIdx.x;
  const bool isGh = blockIdx.y != 0;
  const int n0 = blockIdx.x * 64;
  const int K = isGh ? 512 : 1324;
  const float* W = isGh ? Whh : Wih;
  const float* bias = isGh ? bhh : bih;
  float* C = isGh ? gho : gxo;
  const int wave = tid >> 6, lane = tid & 63, quad = lane >> 4, l16 = lane & 15;

  f32x4 acc[4];
  #pragma unroll
  for (int i = 0; i < 4; ++i) acc[i] = (f32x4){0.f, 0.f, 0.f, 0.f};

  ushort4 rab[2];
  float4 raf[2];
  float4 rb[2];
  auto fetch = [&](int kt) {
    #pragma unroll
    for (int i = 0; i < 2; ++i) {
      int g = tid + i * 256;
      int row = g >> 3, gc = (g & 7) << 2;
      int gk = kt * 32 + gc;
      if (isGh) {
        // K=512, 16 exact k-steps: gk <= 508, always in-bounds
        raf[i] = *(const float4*)(hidden + (size_t)row * 512 + gk);
      } else {
        // x padded to 1344 = 42*32 exact, pads zero: always in-bounds
        rab[i] = *(const ushort4*)(xb + (size_t)row * 1344 + gk);
      }
      rb[i] = make_float4(0.f, 0.f, 0.f, 0.f);
      if (gk < K) rb[i] = *(const float4*)(W + (size_t)(n0 + row) * K + gk);
    }
  };
  auto stage = [&](int buf) {
    #pragma unroll
    for (int i = 0; i < 2; ++i) {
      int g = tid + i * 256;
      int row = g >> 3, gc = (g & 7) << 2;
      ushort4 a = isGh
          ? make_ushort4(f2b(raf[i].x), f2b(raf[i].y), f2b(raf[i].z), f2b(raf[i].w))
          : rab[i];
      *(ushort4*)(sA[buf] + row * 40 + gc) = a;
      *(ushort4*)(sB[buf] + row * 40 + gc) =
          make_ushort4(f2b(rb[i].x), f2b(rb[i].y), f2b(rb[i].z), f2b(rb[i].w));
    }
  };
  const int ksteps = isGh ? 16 : 42;
  fetch(0);
  stage(0);
  fetch(1);
  __syncthreads();
  for (int kt = 0; kt < ksteps; ++kt) {
    if (kt + 1 < ksteps) stage((kt + 1) & 1);
    if (kt + 2 < ksteps) fetch(kt + 2);
    bf16x8 af = *(const bf16x8*)(sA[kt & 1] + (wave * 16 + l16) * 40 + quad * 8);
    #pragma unroll
    for (int nt = 0; nt < 4; ++nt) {
      bf16x8 bfr = *(const bf16x8*)(sB[kt & 1] + (nt * 16 + l16) * 40 + quad * 8);
      acc[nt] = __builtin_amdgcn_mfma_f32_16x16x32_bf16(af, bfr, acc[nt], 0, 0, 0);
    }
    __syncthreads();
  }
  #pragma unroll
  for (int nt = 0; nt < 4; ++nt) {
    #pragma unroll
    for (int reg = 0; reg < 4; ++reg) {
      int row = wave * 16 + quad * 4 + reg;
      int col = n0 + nt * 16 + l16;
      C[(size_t)row * 1536 + col] = acc[nt][reg] + bias[col];
    }
  }
}

// ---------------------------------------------------------------------------
// GRU pointwise: r,z,n -> h_new (to out + xo[:,0:512])
// ---------------------------------------------------------------------------
__global__ __launch_bounds__(256) void gru_pointwise(
    const float* __restrict__ gx,       // [64, 1536]
    const float* __restrict__ gh,       // [64, 1536]
    const float* __restrict__ hidden,   // [64, 512]
    float* __restrict__ out,            // h_new at HNEW_OFS
    ushort_t* __restrict__ xo)          // [64, 1856]
{
  int i = blockIdx.x * 256 + threadIdx.x;   // 0..32767
  int b = i >> 9, h = i & 511;
  float r = fast_sigmoid(gx[b * 1536 + h] + gh[b * 1536 + h]);
  float z = fast_sigmoid(gx[b * 1536 + 512 + h] + gh[b * 1536 + 512 + h]);
  float n = fast_tanh(gx[b * 1536 + 1024 + h] + r * gh[b * 1536 + 1024 + h]);
  float hp = hidden[b * 512 + h];
  float hn = (1.f - z) * n + z * hp;
  out[HNEW_OFS + b * 512 + h] = hn;
  xo[b * 1856 + h] = f2b(hn);
}

// ---------------------------------------------------------------------------
// Output projection: pred[64,50257] = xo[64,1836] @ W_out[50257,1836]^T + b_out
// HBM-bound (369 MB f32 W_out, zero reuse): B streams global->reg->bf16->MFMA,
// 2-step register double-buffer, no LDS bounce; A (Xo) LDS double-buffered.
// ---------------------------------------------------------------------------
__global__ __launch_bounds__(256) void out_proj2(
    const ushort_t* __restrict__ Xo,     // [64, 1856] bf16 (cols 1836.. zero)
    const float* __restrict__ Wout,      // [50257, 1836] f32
    const float* __restrict__ bout,      // [50257]
    float* __restrict__ pred)            // [64, 50257]
{
  __shared__ ushort_t sA[2][64 * 40];
  const int tid = threadIdx.x;
  const int n0 = blockIdx.x * 64;
  const int wave = tid >> 6, lane = tid & 63, quad = lane >> 4, l16 = lane & 15;

  // this lane's W_out row (= output column)
  const int col = n0 + wave * 16 + l16;
  const int colc = (col < V_) ? col : 0;
  const float* pB = Wout + (size_t)colc * 1836;

  // A staging: thread t covers Xo[t>>2][(t&3)*8 + kt*32 .. +7] (16 B)
  const int arow = tid >> 2;
  const int acol = (tid & 3) * 8;
  const ushort_t* pA = Xo + (size_t)arow * 1856 + acol;
  ushort_t* sAw0 = &sA[0][arow * 40 + acol];
  ushort_t* sAw1 = &sA[1][arow * 40 + acol];

  f32x4 acc[4];
  #pragma unroll
  for (int i = 0; i < 4; ++i) acc[i] = (f32x4){0.f, 0.f, 0.f, 0.f};

  float4 b0a, b0b, b1a, b1b;
  auto ldB = [&](int kt, float4& va, float4& vb) {
    int k0 = kt * 32 + quad * 8;
    int ka = (k0 < 1832) ? k0 : 1832;
    int kb = (k0 + 4 < 1832) ? (k0 + 4) : 1832;
    va = *(const float4*)(pB + ka);
    vb = *(const float4*)(pB + kb);
  };
  auto packB = [](float4 a, float4 b) {
    bf16x8 r;
    r[0] = (short)f2b(a.x); r[1] = (short)f2b(a.y);
    r[2] = (short)f2b(a.z); r[3] = (short)f2b(a.w);
    r[4] = (short)f2b(b.x); r[5] = (short)f2b(b.y);
    r[6] = (short)f2b(b.z); r[7] = (short)f2b(b.w);
    return r;
  };
  auto mfma4 = [&](const ushort_t* base, bf16x8 bf) {
    #pragma unroll
    for (int mt = 0; mt < 4; ++mt) {
      bf16x8 af = *(const bf16x8*)(base + (mt * 16 + l16) * 40 + quad * 8);
      acc[mt] = __builtin_amdgcn_mfma_f32_16x16x32_bf16(af, bf, acc[mt], 0, 0, 0);
    }
  };

  // prologue: sA[0] <- A(0); regs: aReg=A(1), b0=B(0), b1=B(1)
  ldB(0, b0a, b0b);
  bf16x8 aReg = *(const bf16x8*)(pA);
  *(bf16x8*)sAw0 = aReg;
  aReg = *(const bf16x8*)(pA + 32);
  ldB(1, b1a, b1b);
  __syncthreads();

  // 58 k-steps (K=1836 padded to 1856), 2 per iteration (named reg dbuf)
  #pragma unroll 1
  for (int kt = 0; kt < 58; kt += 2) {
    // even step kt: consume b0 + sA[0]; stage A(kt+1)->sA[1]
    {
      if (kt + 1 < 58) *(bf16x8*)sAw1 = aReg;
      bf16x8 bf = packB(b0a, b0b);
      if (kt + 2 < 58) {
        ldB(kt + 2, b0a, b0b);
        aReg = *(const bf16x8*)(pA + (size_t)(kt + 2) * 32);
      }
      mfma4(&sA[0][0], bf);
      __syncthreads();
    }
    // odd step kt+1: consume b1 + sA[1]; stage A(kt+2)->sA[0]
    {
      if (kt + 3 < 58) *(bf16x8*)sAw0 = aReg;
      bf16x8 bf = packB(b1a, b1b);
      if (kt + 3 < 58) {
        ldB(kt + 3, b1a, b1b);
        aReg = *(const bf16x8*)(pA + (size_t)(kt + 3) * 32);
      }
      mfma4(&sA[1][0], bf);
      __syncthreads();
    }
  }

  if (col < V_) {
    float bc = bout[col];
    #pragma unroll
    for (int mt = 0; mt < 4; ++mt) {
      #pragma unroll
      for (int reg = 0; reg < 4; ++reg) {
        int prow = mt * 16 + quad * 4 + reg;
        pred[(size_t)prow * V_ + col] = acc[mt][reg] + bc;
      }
    }
  }
}

// ---------------------------------------------------------------------------
extern "C" void kernel_launch(void* const* d_in, const int* in_sizes, int n_in,
                              void* d_out, int out_size, void* d_ws, size_t ws_size,
                              hipStream_t stream) {
  const int*   ids    = (const int*)d_in[0];
  const float* hidden = (const float*)d_in[1];
  const float* enc    = (const float*)d_in[2];
  const int*   mask   = (const int*)d_in[3];
  const float* emb    = (const float*)d_in[4];
  const float* Wattn  = (const float*)d_in[5];
  const float* battn  = (const float*)d_in[6];
  const float* vw     = (const float*)d_in[7];
  const float* Wih    = (const float*)d_in[8];
  const float* Whh    = (const float*)d_in[9];
  const float* bih    = (const float*)d_in[10];
  const float* bhh    = (const float*)d_in[11];
  const float* Wout   = (const float*)d_in[12];
  const float* bout   = (const float*)d_in[13];
  float* out = (float*)d_out;

  char* ws = (char*)d_ws;
  float*    scores_part = (float*)(ws + 0);          // 8*8192 f32 = 256 KB
  float*    Gh          = (float*)(ws + 262144);     // 64*512 f32 = 128 KB
  float*    gx          = (float*)(ws + 393216);     // 64*1536 f32 = 384 KB
  float*    gh          = (float*)(ws + 786432);     // 64*1536 f32 = 384 KB
  ushort_t* x           = (ushort_t*)(ws + 1179648); // 64*1344 bf16 = 168 KB
  ushort_t* xo          = (ushort_t*)(ws + 1351680); // 64*1856 bf16 = 232 KB

  // Gh = hidden @ Wattn[:, 0:512]^T + b_attn
  gemm_tile<1, 1><<<dim3(8, 1), 256, 0, stream>>>(
      hidden, 512, Wattn, 1536, 0, battn, Gh, 512, 64, 512, 512);

  // partial attention scores (fused energy GEMM + tanh + v-dot)
  attn_scores<<<dim3(8, 128), 256, 0, stream>>>(enc, Wattn, Gh, vw, scores_part);

  // softmax + context + build x, xo (+ a output)
  softmax_ctx<<<64, 256, 0, stream>>>(scores_part, mask, enc, emb, ids, out, x, xo);

  // gx = x @ W_ih^T + b_ih ; gh = hidden @ W_hh^T + b_hh  (one fused launch)
  gemm_gxgh<<<dim3(24, 2), 256, 0, stream>>>(
      x, hidden, Wih, Whh, bih, bhh, gx, gh);

  // GRU pointwise -> h_new
  gru_pointwise<<<128, 256, 0, stream>>>(gx, gh, hidden, out, xo);

  // prediction = xo @ W_out^T + b_out (B streamed global->reg, no LDS)
  out_proj2<<<786, 256, 0, stream>>>(xo, Wout, bout, out);
}